// Round 5
// baseline (407.617 us; speedup 1.0000x reference)
//
#include <hip/hip_runtime.h>
#include <math.h>

// CapsuleLayer dynamic routing, fp32, MI355X (gfx950).
// B=64, IN_CAPS=2048, IN_DIM=8, OUT_CAPS=32, OUT_DIM=16, 3 routing iters.
//
// b_ij after r updates = u_hat_i . (v0+...+v_{r-1}) (b starts at 0), so no
// u_hat materialization: each pass recomputes u_hat from W via LDS staging.
//
// R6 -> R7: R6 (256-thr blocks, grid 512 = 2 blk/CU = 8 waves/CU, 172 VGPR)
// hit 169.8us. Per-CU arithmetic says LDS ~10us / VALU ~11us per pass, so
// the ~35us pass is lockstep-stall-bound: only 2 independent blocks/CU to
// cover each other's __syncthreads+vmcnt drains. 172 VGPR is 2 regs over
// the 3-waves/SIMD line (3x170=510<=512). R7: (a) jj-loop split into two
// halves -> wA/wB live 64->32 floats (real ~32-reg saving, not a forced
// cap); (b) __launch_bounds__(256,3) pins alloc <=170; (c) IB=8 -> grid
// 1024 = 3 resident blocks/CU (LDS 3x33.8=101KB fits). 12 waves/CU.

#define IC 2048
#define ID 8
#define OC 32
#define OD 16
#define B_N 64
#define S_ELEMS (B_N * OC * OD)   // 32768
#define IB 8                      // i's per block
#define ISTR (IC / IB)            // 256 i-stripes
#define BPB 16                    // b's per block (4 per wave)
#define BG (B_N / BPB)            // 4 b-groups

// async 16B global->LDS (direct, no VGPR round trip)
__device__ __forceinline__ void gll16(const float4* g, float4* l)
{
    __builtin_amdgcn_global_load_lds(
        (const __attribute__((address_space(1))) void*)g,
        (__attribute__((address_space(3))) void*)l,
        16, 0, 0);
}

// x + dpp_perm(x) on the VALU pipe (no LDS traffic)
template <int CTRL>
__device__ __forceinline__ float dpp_add(float x)
{
    union { float f; int i; } a, b;
    a.f = x;
    b.i = __builtin_amdgcn_update_dpp(0, a.i, CTRL, 0xF, 0xF, true);
    return x + b.f;
}

// W tile i is 1024 float4 "chunks"; global chunk f = (o*16 + j)*2 + dq.
// LDS layout: row o (32 chunks), chunk slot = (j*2+dq) ^ o.  Staging dest is
// linear D = s*256+tid; the matching pre-swizzled source is
//   f(D) = (D>>5)*32 + ((D&31) ^ (D>>5)).
// Hot read, fixed (jj,dq): lanes (o,jh) hit slot ((jh*16+jj*2+dq)^o) in row o
// -> slot%8 uniform over lanes -> conflict-free b128.

template <int FIRST>
__launch_bounds__(256, 3)
__global__ void caps_pass(const float* __restrict__ Wg,
                          const float* __restrict__ xg,
                          const float* __restrict__ vs,
                          float* __restrict__ part)
{
    __shared__ float4 Wl[2][1024];      // 32 KB, double-buffered W tile
    __shared__ float4 xsh[2][BPB * 2];  // 1 KB, x fragments

    const int tid  = threadIdx.x;
    const int lane = tid & 63;
    const int w    = tid >> 6;        // wave 0..3
    const int o    = lane & 31;
    const int jh   = lane >> 5;

    const int is   = blockIdx.x & (ISTR - 1);  // same-W blocks are 256 apart
    const int bg   = blockIdx.x >> 8;          // -> land on the same XCD
    const int bblk = bg * BPB;

    const float4* wq = (const float4*)Wg;

    // v-sum fragments for this wave's 4 b's, held across the i-loop
    float4 va[4], vb[4];
    if (!FIRST) {
#pragma unroll
        for (int n = 0; n < 4; ++n) {
            const float* vp =
                vs + (size_t)(bblk + w * 4 + n) * (OC * OD) + o * OD + jh * 8;
            va[n] = ((const float4*)vp)[0];
            vb[n] = ((const float4*)vp)[1];
        }
    }

    float acc[4][8];
#pragma unroll
    for (int n = 0; n < 4; ++n)
#pragma unroll
        for (int jj = 0; jj < 8; ++jj) acc[n][jj] = 0.0f;

    // ---- prologue: stage tile 0 into parity 0
    {
        const int ig = is * IB;
        const size_t wb0 = (size_t)ig * 1024;
#pragma unroll
        for (int s = 0; s < 4; ++s) {
            const int D = s * 256 + tid;
            const int orow = D >> 5;
            const int f = orow * 32 + ((D & 31) ^ orow);
            gll16(wq + wb0 + f, &Wl[0][D]);
        }
        if (tid < 32)
            xsh[0][tid] = ((const float4*)xg)
                [((size_t)(bblk + (tid >> 1)) * IC + ig) * 2 + (tid & 1)];
    }

    for (int il = 0; il < IB; ++il) {
        const int p = il & 1;
        __syncthreads();   // drains tile(il) loads; nobody reads parity p^1

        // issue next tile's async loads immediately (hide under compute)
        float4 gx = {};
        const bool more = (il + 1 < IB);
        if (more) {
            const int ig = is * IB + il + 1;
            const size_t wb0 = (size_t)ig * 1024;
#pragma unroll
            for (int s = 0; s < 4; ++s) {
                const int D = s * 256 + tid;
                const int orow = D >> 5;
                const int f = orow * 32 + ((D & 31) ^ orow);
                gll16(wq + wb0 + f, &Wl[p ^ 1][D]);
            }
            if (tid < 32)
                gx = ((const float4*)xg)
                    [((size_t)(bblk + (tid >> 1)) * IC + ig) * 2 + (tid & 1)];
        }

        // u_hat in two jj-halves: only 8 W float4s live at a time
        float u[4][8];
        const int row = o * 32;
#pragma unroll
        for (int half = 0; half < 2; ++half) {
            float4 wA[4], wB[4];
#pragma unroll
            for (int q = 0; q < 4; ++q) {
                const int jj = half * 4 + q;
                const int ca = (jh * 16 + jj * 2) ^ o;   // dq=0 slot
                wA[q] = Wl[p][row + ca];
                wB[q] = Wl[p][row + (ca ^ 1)];           // dq=1 slot
            }
#pragma unroll
            for (int n = 0; n < 4; ++n) {
                const float4 xa = xsh[p][(w * 4 + n) * 2];
                const float4 xb = xsh[p][(w * 4 + n) * 2 + 1];
#pragma unroll
                for (int q = 0; q < 4; ++q) {
                    float t = wA[q].x * xa.x;
                    t = fmaf(wA[q].y, xa.y, t);
                    t = fmaf(wA[q].z, xa.z, t);
                    t = fmaf(wA[q].w, xa.w, t);
                    t = fmaf(wB[q].x, xb.x, t);
                    t = fmaf(wB[q].y, xb.y, t);
                    t = fmaf(wB[q].z, xb.z, t);
                    t = fmaf(wB[q].w, xb.w, t);
                    u[n][half * 4 + q] = t;
                }
            }
        }

        // routing coefficient + accumulate
#pragma unroll
        for (int n = 0; n < 4; ++n) {
            float cc;
            if (FIRST) {
                cc = 1.0f;  // softmax(0) = 1/32, folded into the store scale
            } else {
                float bp = u[n][0] * va[n].x;
                bp = fmaf(u[n][1], va[n].y, bp);
                bp = fmaf(u[n][2], va[n].z, bp);
                bp = fmaf(u[n][3], va[n].w, bp);
                bp = fmaf(u[n][4], vb[n].x, bp);
                bp = fmaf(u[n][5], vb[n].y, bp);
                bp = fmaf(u[n][6], vb[n].z, bp);
                bp = fmaf(u[n][7], vb[n].w, bp);
                bp += __shfl_xor(bp, 32);            // combine j-halves
                // no max-subtraction: |logit| tiny, exp safe in fp32
                const float e = __expf(bp);
                float t = dpp_add<0xB1>(e);          // quad_perm xor1
                t = dpp_add<0x4E>(t);                // quad_perm xor2
                t = dpp_add<0x124>(t);               // row_ror:4
                t = dpp_add<0x128>(t);               // row_ror:8 -> row sum
                const float se = t + __shfl_xor(t, 16);  // 32-o total
                cc = e * __builtin_amdgcn_rcpf(se);
            }
#pragma unroll
            for (int jj = 0; jj < 8; ++jj)
                acc[n][jj] = fmaf(cc, u[n][jj], acc[n][jj]);
        }

        // x for next tile (race-free: overwritten parity was last read
        // before the barrier at the top of this iteration)
        if (more && tid < 32) xsh[p ^ 1][tid] = gx;
    }

    // disjoint per-(istripe, b) partials — no atomics, no memset needed
    const float scale = FIRST ? (1.0f / 32.0f) : 1.0f;
#pragma unroll
    for (int n = 0; n < 4; ++n) {
        float* dst = part + (size_t)is * S_ELEMS
                   + (size_t)(bblk + w * 4 + n) * (OC * OD) + o * OD + jh * 8;
        float4 lo = {acc[n][0] * scale, acc[n][1] * scale,
                     acc[n][2] * scale, acc[n][3] * scale};
        float4 hi = {acc[n][4] * scale, acc[n][5] * scale,
                     acc[n][6] * scale, acc[n][7] * scale};
        ((float4*)dst)[0] = lo;
        ((float4*)dst)[1] = hi;
    }
}

// Fused 256-way partial reduction + squash, 512 blocks (2/CU).
// Block handles 64 elems; wave w sums stripes k===w (mod 4), coalesced 256B
// wave-loads; 4-way LDS combine; squash over 16-j lane groups.
// MODE 0: vsum = v   MODE 1: vsum += v   MODE 2: out = v
template <int MODE>
__launch_bounds__(256, 4)
__global__ void caps_reduce(const float* __restrict__ part,
                            float* __restrict__ vsum,
                            float* __restrict__ out)
{
    __shared__ float red[4][64];
    const int tid  = threadIdx.x;
    const int w    = tid >> 6;
    const int lane = tid & 63;
    const int e0   = blockIdx.x * 64;

    float s = 0.0f;
#pragma unroll 8
    for (int k = w; k < ISTR; k += 4)
        s += part[(size_t)k * S_ELEMS + e0 + lane];
    red[w][lane] = s;
    __syncthreads();

    if (tid < 64) {
        const float t = red[0][tid] + red[1][tid] + red[2][tid] + red[3][tid];
        float s2 = t * t;               // ||s||^2 over the 16 j's
        s2 += __shfl_xor(s2, 1);
        s2 += __shfl_xor(s2, 2);
        s2 += __shfl_xor(s2, 4);
        s2 += __shfl_xor(s2, 8);
        const float v = t * (s2 / ((1.0f + s2) * sqrtf(s2 + 1e-9f)));
        const int e = e0 + tid;
        if (MODE == 0)      vsum[e] = v;
        else if (MODE == 1) vsum[e] += v;
        else                out[e] = v;
    }
}

extern "C" void kernel_launch(void* const* d_in, const int* in_sizes, int n_in,
                              void* d_out, int out_size, void* d_ws, size_t ws_size,
                              hipStream_t stream)
{
    const float* x = (const float*)d_in[0];   // [64, 2048, 8]
    const float* W = (const float*)d_in[1];   // [1, 2048, 32, 16, 8]
    float* out = (float*)d_out;               // [64, 32, 16]

    float* part = (float*)d_ws;                        // 256 x 32768 = 33.5 MB
    float* vsum = part + (size_t)ISTR * S_ELEMS;       // 32768 floats

    const dim3 gP(BG * ISTR);     // 1024 blocks
    const dim3 bP(256);
    const dim3 gR(S_ELEMS / 64);  // 512 blocks
    const dim3 bR(256);

    // round 0: c uniform
    caps_pass<1><<<gP, bP, 0, stream>>>(W, x, nullptr, part);
    caps_reduce<0><<<gR, bR, 0, stream>>>(part, vsum, out);   // vsum = v0
    // round 1: b = u.v0
    caps_pass<0><<<gP, bP, 0, stream>>>(W, x, vsum, part);
    caps_reduce<1><<<gR, bR, 0, stream>>>(part, vsum, out);   // vsum = v0+v1
    // round 2: b = u.(v0+v1)
    caps_pass<0><<<gP, bP, 0, stream>>>(W, x, vsum, part);
    caps_reduce<2><<<gR, bR, 0, stream>>>(part, vsum, out);   // out = v2
}

// Round 6
// 170.162 us; speedup vs baseline: 2.3955x; 2.3955x over previous
//
#include <hip/hip_runtime.h>
#include <math.h>

// CapsuleLayer dynamic routing, fp32, MI355X (gfx950).
// B=64, IN_CAPS=2048, IN_DIM=8, OUT_CAPS=32, OUT_DIM=16, 3 routing iters.
//
// b_ij after r updates = u_hat_i . (v0+...+v_{r-1}) (b starts at 0), so no
// u_hat materialization: each pass recomputes u_hat from W via LDS staging.
//
// R7 -> R8: R4/R7 proved any __launch_bounds__ VGPR pressure spills (~170
// live regs needed); 2 waves/SIMD is the hard occupancy cap. R6 (169.8us,
// 172 VGPR, (256,2)) is the base. R8 attacks exposed stall per iteration
// instead of occupancy:
//  - x preloaded ONCE to LDS in prologue (8KB): no per-iter x staging, no
//    divergent tid<32 path, no lgkm-coupled ds_write on the barrier path.
//  - W: 4-deep LDS buffers (64KB), staged 2 tiles ahead via global_load_lds;
//    loop barrier is raw s_barrier preceded by COUNTED s_waitcnt vmcnt(8)
//    (T3/T4: never drain to 0 mid-loop) -> each tile gets ~2 compute phases
//    (~3300cyc >> 900cyc HBM) and prefetch stays in flight across barriers.
//    Last two iterations peeled with vmcnt(4)/vmcnt(0).
// LDS 72.3KB/block x 2 blocks/CU = 145KB <= 160KB. Compute body identical
// to R6 (XOR-swizzled conflict-free ds_read_b128, DPP softmax).

#define IC 2048
#define ID 8
#define OC 32
#define OD 16
#define B_N 64
#define S_ELEMS (B_N * OC * OD)   // 32768
#define IB 16                     // i's per block
#define ISTR (IC / IB)            // 128 i-stripes
#define BPB 16                    // b's per block (4 per wave)
#define BG (B_N / BPB)            // 4 b-groups

// async 16B global->LDS (direct, no VGPR round trip)
__device__ __forceinline__ void gll16(const float4* g, float4* l)
{
    __builtin_amdgcn_global_load_lds(
        (const __attribute__((address_space(1))) void*)g,
        (__attribute__((address_space(3))) void*)l,
        16, 0, 0);
}

// x + dpp_perm(x) on the VALU pipe (no LDS traffic)
template <int CTRL>
__device__ __forceinline__ float dpp_add(float x)
{
    union { float f; int i; } a, b;
    a.f = x;
    b.i = __builtin_amdgcn_update_dpp(0, a.i, CTRL, 0xF, 0xF, true);
    return x + b.f;
}

// W tile i is 1024 float4 "chunks"; global chunk f = (o*16 + j)*2 + dq.
// LDS layout: row o (32 chunks), chunk slot = (j*2+dq) ^ o.  Staging dest is
// linear D = s*256+tid; the matching pre-swizzled source is
//   f(D) = (D>>5)*32 + ((D&31) ^ (D>>5)).
// Hot read, fixed (jj,dq): lanes (o,jh) hit slot ((jh*16+jj*2+dq)^o) in row o
// -> slot%8 uniform over lanes -> conflict-free b128.

template <int FIRST>
__launch_bounds__(256, 2)
__global__ void caps_pass(const float* __restrict__ Wg,
                          const float* __restrict__ xg,
                          const float* __restrict__ vs,
                          float* __restrict__ part)
{
    __shared__ float4 Wl[4][1024];      // 64 KB, 4-deep W tiles
    __shared__ float4 xs[BPB * 32];     // 8 KB: x[b][i][h], all 16 i's

    const int tid  = threadIdx.x;
    const int lane = tid & 63;
    const int w    = tid >> 6;        // wave 0..3
    const int o    = lane & 31;
    const int jh   = lane >> 5;

    const int is   = blockIdx.x & (ISTR - 1);  // same-W blocks are 128 apart
    const int bg   = blockIdx.x >> 7;          // -> land on the same XCD
    const int bblk = bg * BPB;
    const int ig0  = is * IB;

    const float4* wq = (const float4*)Wg;
    const float4* xq = (const float4*)xg;

    // v-sum fragments for this wave's 4 b's, held across the i-loop
    float4 va[4], vb[4];
    if (!FIRST) {
#pragma unroll
        for (int n = 0; n < 4; ++n) {
            const float* vp =
                vs + (size_t)(bblk + w * 4 + n) * (OC * OD) + o * OD + jh * 8;
            va[n] = ((const float4*)vp)[0];
            vb[n] = ((const float4*)vp)[1];
        }
    }

    float acc[4][8];
#pragma unroll
    for (int n = 0; n < 4; ++n)
#pragma unroll
        for (int jj = 0; jj < 8; ++jj) acc[n][jj] = 0.0f;

    // stage W tile t into Wl[t&3] (4 gll16 wave-instructions)
    auto stage = [&](int t) {
        const size_t wb0 = (size_t)(ig0 + t) * 1024;
        float4* dst = Wl[t & 3];
#pragma unroll
        for (int s = 0; s < 4; ++s) {
            const int D = s * 256 + tid;
            const int orow = D >> 5;
            const int f = orow * 32 + ((D & 31) ^ orow);
            gll16(wq + wb0 + f, dst + D);
        }
    };

    // ---- prologue: W tiles 0,1 + ALL x for this (b-group, i-stripe)
    stage(0);
    stage(1);
    {
        // xs slot s = b*32 + i*2 + h  <-  xq[((bblk+b)*IC + ig0)*2 + i*2+h]
        // two gll16 per thread, dest linear in lane within each wave
#pragma unroll
        for (int q = 0; q < 2; ++q) {
            const int s = q * 256 + tid;
            const int b = s >> 5;
            const int r = s & 31;
            gll16(xq + ((size_t)(bblk + b) * IC + ig0) * 2 + r, &xs[s]);
        }
    }

    // compute one i-tile from Wl[il&3] (identical math to R6)
    auto compute = [&](int il) {
        float4 wA[8], wB[8];
        const float4* buf = Wl[il & 3];
        const int row = o * 32;
#pragma unroll
        for (int jj = 0; jj < 8; ++jj) {
            const int ca = (jh * 16 + jj * 2) ^ o;   // dq=0 slot
            wA[jj] = buf[row + ca];
            wB[jj] = buf[row + (ca ^ 1)];            // dq=1 slot
        }

#pragma unroll
        for (int n = 0; n < 4; ++n) {
            const float4 xa = xs[(w * 4 + n) * 32 + il * 2];
            const float4 xb = xs[(w * 4 + n) * 32 + il * 2 + 1];
            float u[8];
#pragma unroll
            for (int jj = 0; jj < 8; ++jj) {
                float t = wA[jj].x * xa.x;
                t = fmaf(wA[jj].y, xa.y, t);
                t = fmaf(wA[jj].z, xa.z, t);
                t = fmaf(wA[jj].w, xa.w, t);
                t = fmaf(wB[jj].x, xb.x, t);
                t = fmaf(wB[jj].y, xb.y, t);
                t = fmaf(wB[jj].z, xb.z, t);
                t = fmaf(wB[jj].w, xb.w, t);
                u[jj] = t;
            }
            float cc;
            if (FIRST) {
                cc = 1.0f;  // softmax(0) = 1/32, folded into the store scale
            } else {
                float bp = u[0] * va[n].x;
                bp = fmaf(u[1], va[n].y, bp);
                bp = fmaf(u[2], va[n].z, bp);
                bp = fmaf(u[3], va[n].w, bp);
                bp = fmaf(u[4], vb[n].x, bp);
                bp = fmaf(u[5], vb[n].y, bp);
                bp = fmaf(u[6], vb[n].z, bp);
                bp = fmaf(u[7], vb[n].w, bp);
                bp += __shfl_xor(bp, 32);            // combine j-halves
                // no max-subtraction: |logit| tiny, exp safe in fp32
                const float e = __expf(bp);
                float t = dpp_add<0xB1>(e);          // quad_perm xor1
                t = dpp_add<0x4E>(t);                // quad_perm xor2
                t = dpp_add<0x124>(t);               // row_ror:4
                t = dpp_add<0x128>(t);               // row_ror:8 -> row sum
                const float se = t + __shfl_xor(t, 16);  // 32-o total
                cc = e * __builtin_amdgcn_rcpf(se);
            }
#pragma unroll
            for (int jj = 0; jj < 8; ++jj)
                acc[n][jj] = fmaf(cc, u[jj], acc[n][jj]);
        }
    };

    // ---- main loop: stage 2 ahead, counted vmcnt (never 0 mid-loop).
    // At iter il: outstanding newer loads = tiles il+1, il+2 (4 each);
    // vmcnt(8) -> tile il (and, first iter, the x preload) has landed.
    for (int il = 0; il < IB - 2; ++il) {
        stage(il + 2);
        asm volatile("s_waitcnt vmcnt(8)" ::: "memory");
        __builtin_amdgcn_s_barrier();
        compute(il);
    }
    // peel: il = IB-2 (one stage still in flight), il = IB-1 (none)
    asm volatile("s_waitcnt vmcnt(4)" ::: "memory");
    __builtin_amdgcn_s_barrier();
    compute(IB - 2);
    asm volatile("s_waitcnt vmcnt(0)" ::: "memory");
    __builtin_amdgcn_s_barrier();
    compute(IB - 1);

    // disjoint per-(istripe, b) partials — no atomics, no memset needed
    const float scale = FIRST ? (1.0f / 32.0f) : 1.0f;
#pragma unroll
    for (int n = 0; n < 4; ++n) {
        float* dst = part + (size_t)is * S_ELEMS
                   + (size_t)(bblk + w * 4 + n) * (OC * OD) + o * OD + jh * 8;
        float4 lo = {acc[n][0] * scale, acc[n][1] * scale,
                     acc[n][2] * scale, acc[n][3] * scale};
        float4 hi = {acc[n][4] * scale, acc[n][5] * scale,
                     acc[n][6] * scale, acc[n][7] * scale};
        ((float4*)dst)[0] = lo;
        ((float4*)dst)[1] = hi;
    }
}

// Fused 128-way partial reduction + squash, 512 blocks (2/CU).
// Block handles 64 elems; wave w sums stripes k===w (mod 4), coalesced 256B
// wave-loads; 4-way LDS combine; squash over 16-j lane groups.
// MODE 0: vsum = v   MODE 1: vsum += v   MODE 2: out = v
template <int MODE>
__launch_bounds__(256, 4)
__global__ void caps_reduce(const float* __restrict__ part,
                            float* __restrict__ vsum,
                            float* __restrict__ out)
{
    __shared__ float red[4][64];
    const int tid  = threadIdx.x;
    const int w    = tid >> 6;
    const int lane = tid & 63;
    const int e0   = blockIdx.x * 64;

    float s = 0.0f;
#pragma unroll 8
    for (int k = w; k < ISTR; k += 4)
        s += part[(size_t)k * S_ELEMS + e0 + lane];
    red[w][lane] = s;
    __syncthreads();

    if (tid < 64) {
        const float t = red[0][tid] + red[1][tid] + red[2][tid] + red[3][tid];
        float s2 = t * t;               // ||s||^2 over the 16 j's
        s2 += __shfl_xor(s2, 1);
        s2 += __shfl_xor(s2, 2);
        s2 += __shfl_xor(s2, 4);
        s2 += __shfl_xor(s2, 8);
        const float v = t * (s2 / ((1.0f + s2) * sqrtf(s2 + 1e-9f)));
        const int e = e0 + tid;
        if (MODE == 0)      vsum[e] = v;
        else if (MODE == 1) vsum[e] += v;
        else                out[e] = v;
    }
}

extern "C" void kernel_launch(void* const* d_in, const int* in_sizes, int n_in,
                              void* d_out, int out_size, void* d_ws, size_t ws_size,
                              hipStream_t stream)
{
    const float* x = (const float*)d_in[0];   // [64, 2048, 8]
    const float* W = (const float*)d_in[1];   // [1, 2048, 32, 16, 8]
    float* out = (float*)d_out;               // [64, 32, 16]

    float* part = (float*)d_ws;                        // 128 x 32768 = 16.8 MB
    float* vsum = part + (size_t)ISTR * S_ELEMS;       // 32768 floats

    const dim3 gP(BG * ISTR);     // 512 blocks
    const dim3 bP(256);
    const dim3 gR(S_ELEMS / 64);  // 512 blocks
    const dim3 bR(256);

    // round 0: c uniform
    caps_pass<1><<<gP, bP, 0, stream>>>(W, x, nullptr, part);
    caps_reduce<0><<<gR, bR, 0, stream>>>(part, vsum, out);   // vsum = v0
    // round 1: b = u.v0
    caps_pass<0><<<gP, bP, 0, stream>>>(W, x, vsum, part);
    caps_reduce<1><<<gR, bR, 0, stream>>>(part, vsum, out);   // vsum = v0+v1
    // round 2: b = u.(v0+v1)
    caps_pass<0><<<gP, bP, 0, stream>>>(W, x, vsum, part);
    caps_reduce<2><<<gR, bR, 0, stream>>>(part, vsum, out);   // out = v2
}